// Round 1
// baseline (90.933 us; speedup 1.0000x reference)
//
#include <hip/hip_runtime.h>

#define B_ 64
#define S_ 512
#define H_ 768
#define L_ 9

__device__ __forceinline__ float rlf(float x, int i) {
    return __int_as_float(__builtin_amdgcn_readlane(__float_as_int(x), i));
}

// ---------------------------------------------------------------------------
// Kernel A: emissions = hidden @ W + b, skipping masked-out rows.
// One wave per 4 rows; W columns for this lane's k-set live in VGPRs.
// ---------------------------------------------------------------------------
__global__ __launch_bounds__(256, 2) void emis_kernel(
    const float* __restrict__ hidden, const float* __restrict__ W,
    const float* __restrict__ bias, const int* __restrict__ lengths,
    float* __restrict__ em)
{
    const int lane = threadIdx.x & 63;
    const int wave = (blockIdx.x << 2) + (threadIdx.x >> 6);

    // k-set for this lane: k = 256*j + 4*lane + d   (j=0..2, d=0..3)
    float Wreg[12][9];
    #pragma unroll
    for (int j = 0; j < 3; ++j) {
        #pragma unroll
        for (int d = 0; d < 4; ++d) {
            const int k = 256 * j + 4 * lane + d;
            #pragma unroll
            for (int l = 0; l < 9; ++l)
                Wreg[j * 4 + d][l] = W[k * 9 + l];
        }
    }
    const float bl = (lane < 9) ? bias[lane] : 0.0f;

    #pragma unroll
    for (int rr = 0; rr < 4; ++rr) {
        const int row = (wave << 2) + rr;          // 0 .. 32767
        const int b = row >> 9, s = row & 511;
        int len = lengths[b]; if (len < 1) len = 1;
        if (s >= len) continue;                    // emission never used

        const float4* h4 = (const float4*)(hidden + (size_t)row * H_);
        float acc[9];
        #pragma unroll
        for (int l = 0; l < 9; ++l) acc[l] = 0.0f;

        #pragma unroll
        for (int j = 0; j < 3; ++j) {
            float4 h = h4[j * 64 + lane];
            const float* hp = &h.x;
            #pragma unroll
            for (int d = 0; d < 4; ++d) {
                const float hv = hp[d];
                #pragma unroll
                for (int l = 0; l < 9; ++l)
                    acc[l] = fmaf(hv, Wreg[j * 4 + d][l], acc[l]);
            }
        }
        // reduce 9 partials across 64 lanes
        #pragma unroll
        for (int off = 32; off >= 1; off >>= 1) {
            #pragma unroll
            for (int l = 0; l < 9; ++l)
                acc[l] += __shfl_xor(acc[l], off, 64);
        }
        // lane l stores acc[l]
        float v = acc[0];
        #pragma unroll
        for (int l = 1; l < 9; ++l)
            if (lane == l) v = acc[l];
        if (lane < 9)
            em[(size_t)row * L_ + lane] = v + bl;
    }
}

// ---------------------------------------------------------------------------
// Kernel B: CRF numerator + forward algorithm (scaled prob space) per batch.
// One wave per batch element. Lanes 0..8 carry the 9 forward states.
// ---------------------------------------------------------------------------
__global__ __launch_bounds__(64, 1) void crf_kernel(
    const float* __restrict__ em_g, const int* __restrict__ labels,
    const int* __restrict__ lengths, const float* __restrict__ start_t,
    const float* __restrict__ trans, const float* __restrict__ end_t,
    float* __restrict__ out)
{
    __shared__ float4 em_s4[(S_ * L_) / 4];   // 18 KiB emissions for this batch
    __shared__ float trans_s[L_ * L_];
    __shared__ int   lab_s[S_];
    float* em_s = (float*)em_s4;
    const int lane = threadIdx.x;
    const int b = blockIdx.x;

    const float4* src = (const float4*)(em_g + (size_t)b * S_ * L_);
    #pragma unroll
    for (int i = 0; i < 18; ++i) em_s4[i * 64 + lane] = src[i * 64 + lane];
    const int4* lsrc = (const int4*)(labels + (size_t)b * S_);
    int4* ldst = (int4*)lab_s;
    #pragma unroll
    for (int i = 0; i < 2; ++i) ldst[i * 64 + lane] = lsrc[i * 64 + lane];
    for (int i = lane; i < L_ * L_; i += 64) trans_s[i] = trans[i];
    __syncthreads();

    int len = lengths[b]; if (len < 1) len = 1;

    // ---- numerator: gold-path score -------------------------------------
    float part = 0.0f;
    for (int t = 1 + lane; t < len; t += 64) {
        const int tp = lab_s[t - 1], tc = lab_s[t];
        part += trans_s[tp * L_ + tc] + em_s[t * L_ + tc];
    }
    #pragma unroll
    for (int off = 32; off >= 1; off >>= 1) part += __shfl_xor(part, off, 64);
    const int lab0 = lab_s[0], labe = lab_s[len - 1];
    const float num = start_t[lab0] + em_s[lab0] + part + end_t[labe];

    // ---- denominator: scaled forward algorithm --------------------------
    const int j = (lane < L_) ? lane : 0;
    float Pcol[9];
    #pragma unroll
    for (int i = 0; i < 9; ++i) Pcol[i] = __expf(trans_s[i * L_ + j]);

    const float a0 = start_t[j] + em_s[j];
    float m0 = (lane < L_) ? a0 : -1e30f;
    #pragma unroll
    for (int off = 8; off >= 1; off >>= 1) m0 = fmaxf(m0, __shfl_xor(m0, off, 16));
    float logZ = m0;
    float fwd = (lane < 16) ? __expf(a0 - logZ) : 0.0f;

    for (int t = 1; t < len; ++t) {
        const float e = __expf(em_s[t * L_ + j]);
        float c0 = rlf(fwd, 0) * Pcol[0];
        float c1 = rlf(fwd, 1) * Pcol[1];
        float c2 = rlf(fwd, 2) * Pcol[2];
        c0 = fmaf(rlf(fwd, 3), Pcol[3], c0);
        c1 = fmaf(rlf(fwd, 4), Pcol[4], c1);
        c2 = fmaf(rlf(fwd, 5), Pcol[5], c2);
        c0 = fmaf(rlf(fwd, 6), Pcol[6], c0);
        c1 = fmaf(rlf(fwd, 7), Pcol[7], c1);
        c2 = fmaf(rlf(fwd, 8), Pcol[8], c2);
        fwd = (c0 + c1 + c2) * e;
        if ((t & 7) == 0) {                      // rescale every 8 steps
            float m = (lane < L_) ? fwd : 0.0f;
            #pragma unroll
            for (int off = 8; off >= 1; off >>= 1)
                m = fmaxf(m, __shfl_xor(m, off, 16));
            logZ += __logf(m);
            fwd *= __builtin_amdgcn_rcpf(m);
        }
    }
    float ev = (lane < L_) ? fwd * __expf(end_t[j]) : 0.0f;
    #pragma unroll
    for (int off = 8; off >= 1; off >>= 1) ev += __shfl_xor(ev, off, 16);
    if (lane == 0) {
        const float den = logZ + __logf(ev);
        atomicAdd(out, den - num);               // output = sum_b (den - num)
    }
}

// ---------------------------------------------------------------------------
extern "C" void kernel_launch(void* const* d_in, const int* in_sizes, int n_in,
                              void* d_out, int out_size, void* d_ws, size_t ws_size,
                              hipStream_t stream)
{
    (void)in_sizes; (void)n_in; (void)out_size; (void)ws_size;
    const float* hidden  = (const float*)d_in[0];
    const float* W       = (const float*)d_in[1];
    const float* bias    = (const float*)d_in[2];
    const float* start_t = (const float*)d_in[3];
    const float* trans   = (const float*)d_in[4];
    const float* end_t   = (const float*)d_in[5];
    const int*   labels  = (const int*)d_in[6];
    const int*   lengths = (const int*)d_in[7];

    float* em  = (float*)d_ws;      // 32768 * 9 floats = 1.18 MB scratch
    float* out = (float*)d_out;

    hipMemsetAsync(out, 0, sizeof(float), stream);
    emis_kernel<<<2048, 256, 0, stream>>>(hidden, W, bias, lengths, em);
    crf_kernel<<<B_, 64, 0, stream>>>(em, labels, lengths, start_t, trans, end_t, out);
}